// Round 6
// baseline (1050.245 us; speedup 1.0000x reference)
//
#include <hip/hip_runtime.h>
#include <math.h>

#define SEQ 2048
#define DMODEL 1024
#define NH 16
#define DK 64
#define BATCH 2

using bf16x8 = __attribute__((ext_vector_type(8))) __bf16;
using bf16x4 = __attribute__((ext_vector_type(4))) __bf16;
using f32x4  = __attribute__((ext_vector_type(4))) float;

__device__ inline f32x4 mfma16(bf16x8 a, bf16x8 b, f32x4 c) {
    return __builtin_amdgcn_mfma_f32_16x16x32_bf16(a, b, c, 0, 0, 0);
}

__device__ inline void load_lds16(const void* g, void* l) {
    __builtin_amdgcn_global_load_lds(
        (const __attribute__((address_space(1))) void*)g,
        (__attribute__((address_space(3))) void*)l, 16, 0, 0);
}

// ---------------------------------------------------------------------------
// fp32 -> bf16 conversion: 3 activations (4096x1024) + 4 weights (1024x1024).
// ---------------------------------------------------------------------------
__global__ __launch_bounds__(256) void conv_bf16(
        const float* __restrict__ q, const float* __restrict__ k,
        const float* __restrict__ v, const float* __restrict__ wq,
        const float* __restrict__ wk, const float* __restrict__ wv,
        const float* __restrict__ wo,
        __bf16* __restrict__ oq, __bf16* __restrict__ ok, __bf16* __restrict__ ov,
        __bf16* __restrict__ owq, __bf16* __restrict__ owk,
        __bf16* __restrict__ owv, __bf16* __restrict__ owo) {
    int bid = blockIdx.x;
    const float* src;
    __bf16* dst;
    size_t off;
    if (bid < 3072) {
        int ti = bid >> 10;
        src = ti == 0 ? q : (ti == 1 ? k : v);
        dst = ti == 0 ? oq : (ti == 1 ? ok : ov);
        off = (size_t)(bid & 1023) * 4096;
    } else {
        int ti = (bid - 3072) >> 8;
        src = ti == 0 ? wq : (ti == 1 ? wk : (ti == 2 ? wv : wo));
        dst = ti == 0 ? owq : (ti == 1 ? owk : (ti == 2 ? owv : owo));
        off = (size_t)((bid - 3072) & 255) * 4096;
    }
    src += off; dst += off;
    const int t = threadIdx.x;
#pragma unroll
    for (int i = 0; i < 4; ++i) {
        float4 x = *(const float4*)(src + t * 4 + i * 1024);
        bf16x4 y;
        y[0] = (__bf16)x.x; y[1] = (__bf16)x.y;
        y[2] = (__bf16)x.z; y[3] = (__bf16)x.w;
        *(bf16x4*)(dst + t * 4 + i * 1024) = y;
    }
}

// ---------------------------------------------------------------------------
// bf16 MFMA GEMM NT (unchanged): C[m,n] = dot(A[m,:], B[n,:]), K=1024.
// mode 0: fp32 out [M][N] ; mode 1: bf16 out [M][N] ; mode 2: bf16 Vt layout.
// ---------------------------------------------------------------------------
__global__ __launch_bounds__(256) void gemm_bf16(const __bf16* __restrict__ A,
                                                 const __bf16* __restrict__ B,
                                                 void* __restrict__ out,
                                                 int mode) {
    __shared__ __align__(16) __bf16 As[8192];
    __shared__ __align__(16) __bf16 Bs[8192];
    const int t    = threadIdx.x;
    const int w    = t >> 6;
    const int lane = t & 63;
    const int m    = lane & 15;
    const int kg   = lane >> 4;
    const int wr   = w >> 1, wc = w & 1;
    const int m0   = blockIdx.y * 128, n0 = blockIdx.x * 128;
    const int N    = gridDim.x * 128;

    f32x4 acc[4][4] = {};

    for (int k0 = 0; k0 < 1024; k0 += 64) {
        __syncthreads();
#pragma unroll
        for (int i = 0; i < 4; ++i) {
            const int blk = w * 4 + i;
            const int mt = blk >> 1, kt = blk & 1;
            const __bf16* ga = A + (size_t)(m0 + mt * 16 + m) * 1024 + k0 + kt * 32 + kg * 8;
            load_lds16(ga, &As[blk * 512]);
            const __bf16* gb = B + (size_t)(n0 + mt * 16 + m) * 1024 + k0 + kt * 32 + kg * 8;
            load_lds16(gb, &Bs[blk * 512]);
        }
        __syncthreads();
#pragma unroll
        for (int kt = 0; kt < 2; ++kt) {
            bf16x8 af[4], bg[4];
#pragma unroll
            for (int i = 0; i < 4; ++i) {
                af[i] = *(const bf16x8*)&As[((wr * 4 + i) * 2 + kt) * 512 + lane * 8];
                bg[i] = *(const bf16x8*)&Bs[((wc * 4 + i) * 2 + kt) * 512 + lane * 8];
            }
#pragma unroll
            for (int i = 0; i < 4; ++i)
#pragma unroll
                for (int j = 0; j < 4; ++j)
                    acc[i][j] = mfma16(af[i], bg[j], acc[i][j]);
        }
    }

#pragma unroll
    for (int i = 0; i < 4; ++i) {
        const int rb = m0 + wr * 64 + i * 16 + kg * 4;
#pragma unroll
        for (int j = 0; j < 4; ++j) {
            const int gc = n0 + wc * 64 + j * 16 + m;
#pragma unroll
            for (int r = 0; r < 4; ++r) {
                const int gr = rb + r;
                const float vv = acc[i][j][r];
                if (mode == 0) {
                    ((float*)out)[(size_t)gr * N + gc] = vv;
                } else if (mode == 1) {
                    ((__bf16*)out)[(size_t)gr * N + gc] = (__bf16)vv;
                } else {
                    const int hh = gr >> 6, dd = gr & 63;
                    const int bb = gc >> 11, ss = gc & 2047;
                    ((__bf16*)out)[(((size_t)bb * NH + hh) * DK + dd) * SEQ + ss] = (__bf16)vv;
                }
            }
        }
    }
}

// ---------------------------------------------------------------------------
// Barrier-free attention: block = (b, 16 q-rows), 16 waves; wave w = head w.
// Each wave: two-pass flash softmax over its head, fully autonomous.
//   Pass1: online per-lane (m,l), combined across the 16-lane group at end.
//   Pass2: recompute S-tile, P = exp(s-m)*invl -> wave-private LDS bounce
//          (C-layout -> B-frag layout) -> PV mfma(V_A, P_B) into O^T regs.
// avg accumulated in shared fp32 LDS via ds_add_f32 (exact), written once.
// Only 2 __syncthreads in the whole kernel.
// ---------------------------------------------------------------------------
__global__ __launch_bounds__(1024) void attn_mfma(const __bf16* __restrict__ Qp,
                                                  const __bf16* __restrict__ Kp,
                                                  const __bf16* __restrict__ Vt,
                                                  __bf16* __restrict__ att,
                                                  float* __restrict__ avg) {
    __shared__ float sAvg[16 * 2052];          // 131.3 KB, stride-2052 (pad)
    __shared__ __bf16 sPb[16 * 640];           // 16 waves x (16 rows x 40 cols)

    const int t    = threadIdx.x;
    const int w    = t >> 6;          // wave id == head id
    const int lane = t & 63;
    const int m    = lane & 15;
    const int kg   = lane >> 4;
    const int q0   = blockIdx.x * 16;
    const int b    = blockIdx.y;
    const int h    = w;

    // zero the shared avg accumulator (wave w owns row w)
    {
        f32x4 z = {0.f, 0.f, 0.f, 0.f};
#pragma unroll
        for (int j = 0; j < 8; ++j)
            *(f32x4*)&sAvg[w * 2052 + lane * 4 + j * 256] = z;
    }
    __syncthreads();

    const __bf16* Qh = Qp + ((size_t)(b * SEQ + q0)) * 1024 + h * 64;
    const __bf16* Kh = Kp + ((size_t)b * SEQ) * 1024 + h * 64;
    const __bf16* Vh = Vt + ((size_t)(b * NH + h)) * DK * SEQ;

    // Q A-frags (lane m -> q-row q0+m)
    bf16x8 a0 = *(const bf16x8*)(Qh + m * 1024 + kg * 8);
    bf16x8 a1 = *(const bf16x8*)(Qh + m * 1024 + kg * 8 + 32);

    // ---- pass 1: online (m,l), per-lane (k = nt*16 + m), rows kg*4+r ----
    f32x4 m4 = {-1e30f, -1e30f, -1e30f, -1e30f};
    f32x4 l4 = {0.f, 0.f, 0.f, 0.f};
    for (int nt = 0; nt < 128; ++nt) {
        const __bf16* Kt = Kh + (size_t)(nt * 16 + m) * 1024 + kg * 8;
        f32x4 c = {};
        c = mfma16(a0, *(const bf16x8*)(Kt), c);
        c = mfma16(a1, *(const bf16x8*)(Kt + 32), c);
#pragma unroll
        for (int r = 0; r < 4; ++r) {
            float s  = c[r] * 0.125f;
            float mn = fmaxf(m4[r], s);
            l4[r] = l4[r] * __expf(m4[r] - mn) + __expf(s - mn);
            m4[r] = mn;
        }
    }
    // combine across the 16-lane group (covers all k for rows kg*4+r)
#pragma unroll
    for (int off = 1; off < 16; off <<= 1) {
#pragma unroll
        for (int r = 0; r < 4; ++r) {
            float mo = __shfl_xor(m4[r], off, 64);
            float lo = __shfl_xor(l4[r], off, 64);
            float mn = fmaxf(m4[r], mo);
            l4[r] = l4[r] * __expf(m4[r] - mn) + lo * __expf(mo - mn);
            m4[r] = mn;
        }
    }
    f32x4 il;
#pragma unroll
    for (int r = 0; r < 4; ++r) il[r] = 1.0f / l4[r];

    // ---- pass 2: recompute, P write (LDS bounce + avg ds_add), PV MFMA ----
    f32x4 ot[4] = {};
    __bf16* pb = &sPb[w * 640];       // wave-private: 16 rows x 40 cols
    for (int p2 = 0; p2 < 64; ++p2) {
        const int k0 = p2 * 32;
        const __bf16* Kt0 = Kh + (size_t)(k0 + m) * 1024 + kg * 8;
        const __bf16* Kt1 = Kh + (size_t)(k0 + 16 + m) * 1024 + kg * 8;
        f32x4 c0 = {}, c1 = {};
        c0 = mfma16(a0, *(const bf16x8*)(Kt0), c0);
        c0 = mfma16(a1, *(const bf16x8*)(Kt0 + 32), c0);
        c1 = mfma16(a0, *(const bf16x8*)(Kt1), c1);
        c1 = mfma16(a1, *(const bf16x8*)(Kt1 + 32), c1);
#pragma unroll
        for (int r = 0; r < 4; ++r) {
            float p0 = __expf(c0[r] * 0.125f - m4[r]) * il[r];
            float p1 = __expf(c1[r] * 0.125f - m4[r]) * il[r];
            pb[(kg * 4 + r) * 40 + m]      = (__bf16)p0;
            pb[(kg * 4 + r) * 40 + 16 + m] = (__bf16)p1;
            atomicAdd(&sAvg[(kg * 4 + r) * 2052 + k0 + m],      p0);
            atomicAdd(&sAvg[(kg * 4 + r) * 2052 + k0 + 16 + m], p1);
        }
        // B-frag: lane -> P[q = m][k0 + kg*8 .. +7]  (wave-private RAW, no barrier)
        bf16x8 pf = *(const bf16x8*)&pb[m * 40 + kg * 8];
#pragma unroll
        for (int dt = 0; dt < 4; ++dt) {
            bf16x8 vf = *(const bf16x8*)(Vh + (size_t)(dt * 16 + m) * SEQ + k0 + kg * 8);
            ot[dt] = mfma16(vf, pf, ot[dt]);
        }
    }

    // ---- store O: lane holds O[q = m][d = dt*16 + kg*4 + r] ----
    {
        __bf16* arow = att + ((size_t)(b * SEQ + q0 + m)) * 1024 + h * 64;
#pragma unroll
        for (int dt = 0; dt < 4; ++dt) {
            bf16x4 o;
#pragma unroll
            for (int r = 0; r < 4; ++r) o[r] = (__bf16)ot[dt][r];
            *(bf16x4*)(arow + dt * 16 + kg * 4) = o;
        }
    }

    // ---- write avg (scaled by 1/NH) once ----
    __syncthreads();
    {
        const float* srow = &sAvg[w * 2052];
        float* drow = avg + ((size_t)(b * SEQ + q0 + w)) * SEQ;
#pragma unroll
        for (int j = 0; j < 8; ++j) {
            f32x4 v = *(const f32x4*)&srow[lane * 4 + j * 256];
            *(f32x4*)&drow[lane * 4 + j * 256] = v * (1.0f / NH);
        }
    }
}

// ---------------------------------------------------------------------------
extern "C" void kernel_launch(void* const* d_in, const int* in_sizes, int n_in,
                              void* d_out, int out_size, void* d_ws, size_t ws_size,
                              hipStream_t stream) {
    const float* query = (const float*)d_in[0];
    const float* key   = (const float*)d_in[1];
    const float* value = (const float*)d_in[2];
    const float* w_q   = (const float*)d_in[3];
    const float* w_k   = (const float*)d_in[4];
    const float* w_v   = (const float*)d_in[5];
    const float* w_o   = (const float*)d_in[6];

    float* out = (float*)d_out;
    float* avg = out + (size_t)BATCH * SEQ * DMODEL;

    __bf16* Xq = (__bf16*)d_ws;            // [4096][1024]
    __bf16* Xk = Xq + 4194304;
    __bf16* Xv = Xk + 4194304;
    __bf16* Wq = Xv + 4194304;             // [1024][1024]
    __bf16* Wk = Wq + 1048576;
    __bf16* Wv = Wk + 1048576;
    __bf16* Wo = Wv + 1048576;
    __bf16* Qr = Wo + 1048576;             // [4096][1024] row-major
    __bf16* Kr = Qr + 4194304;
    __bf16* Vt = Kr + 4194304;             // [b][h][dk][s]
    __bf16* At = Xq;                       // reuse: Xq dead after Q projection

    conv_bf16<<<4096, 256, 0, stream>>>(query, key, value, w_q, w_k, w_v, w_o,
                                        Xq, Xk, Xv, Wq, Wk, Wv, Wo);

    gemm_bf16<<<dim3(8, 32), 256, 0, stream>>>(Xq, Wq, Qr, 1);   // Q row-major
    gemm_bf16<<<dim3(8, 32), 256, 0, stream>>>(Xk, Wk, Kr, 1);   // K row-major
    gemm_bf16<<<dim3(32, 8), 256, 0, stream>>>(Wv, Xv, Vt, 2);   // V^T

    attn_mfma<<<dim3(SEQ / 16, BATCH), 1024, 0, stream>>>(Qr, Kr, Vt, At, avg);

    gemm_bf16<<<dim3(8, 32), 256, 0, stream>>>(At, Wo, out, 0);  // fp32 out
}